// Round 15
// baseline (134.370 us; speedup 1.0000x reference)
//
#include <hip/hip_runtime.h>
#include <math.h>

typedef __attribute__((ext_vector_type(8))) short bf16x8;
typedef __attribute__((ext_vector_type(4))) float f32x4;

#define IC 64
#define OC 128
#define OHW 62
#define LOCS (OHW*OHW)          /* 3844 */
#define BATCH 32
#define Y_SIZE (BATCH*OC*LOCS)  /* 15740928 */
#define UPD_SIZE (OC*IC*9)      /* 73728 */

#define SWZ(w) (((w) & 7) << 3)

__device__ __forceinline__ unsigned short f2bf(float f) {
    unsigned u = __float_as_uint(f);
    unsigned r = (u + 0x7FFFu + ((u >> 16) & 1u)) >> 16;   // RNE
    return (unsigned short)r;
}
__device__ __forceinline__ float bf2f(unsigned short h) {
    return __uint_as_float(((unsigned)h) << 16);
}
// pack hi16(u1)<<16 | hi16(u0) in ONE v_perm
__device__ __forceinline__ unsigned packhi(unsigned u1, unsigned u0) {
    return __builtin_amdgcn_perm(u1, u0, 0x07060302u);
}

// ---------------- K1: weight norm -> wH burst layout [s=ij*2+ch][lg][k][8c]
__global__ void wnorm_kernel(const float* __restrict__ w, short* __restrict__ wH) {
    int k = blockIdx.x;      // 0..127
    int c = threadIdx.x;     // 0..63
    const float* wp = w + ((size_t)k*IC + c)*9;
    float v[9]; float s = 0.f;
#pragma unroll
    for (int t = 0; t < 9; ++t) { v[t] = wp[t]; s += v[t]*v[t]; }
#pragma unroll
    for (int off = 32; off > 0; off >>= 1) s += __shfl_xor(s, off);
    float nrm = sqrtf(s);
    if (nrm == 0.f) nrm = 1.f;
    float inv = 1.f / nrm;
    const int ch = c >> 5, lg = (c >> 3) & 3, pos = c & 7;
#pragma unroll
    for (int t = 0; t < 9; ++t) {
        size_t off = ((size_t)((t*2 + ch)*4 + lg)*128 + k)*8 + pos;
        wH[off] = (short)f2bf(v[t]*inv);
    }
}

// ---------------- K2: conv via 1-term bf16 MFMA + bias + argmax -----------
// 1-D grid 1984 = 8*248 with XCD clustering: xcd = l&7 owns v = xcd*248 +
// (l>>3) -> 4 complete batches per XCD (halo rows + y boundary lines stay
// in one L2). 256 thr = 4 waves; wave wv -> k-range [32wv,32wv+32).
__global__ __launch_bounds__(256, 6) void conv_kernel(
    const float* __restrict__ x, const short* __restrict__ wH,
    const float* __restrict__ bias, float* __restrict__ y,
    int* __restrict__ winners)
{
    __shared__ short xh[3*66*64];    // [i][w(66)][c], bf16 RNE, swizzled; 25344 B
    __shared__ float biasL[OC];      // total ~25.9 KB -> 6 blocks/CU

    const int l = blockIdx.x;
    const int v = (l & 7)*248 + (l >> 3);   // bijective: 1984 = 8*248
    const int b = v / OHW;                   // 248 = 4*62 -> 4 batches/XCD
    const int oh = v - b*OHW;
    const int tid = threadIdx.x;
    if (tid < OC) biasL[tid] = bias[tid];

    // stage x[b,:,oh..oh+2,:] -> bf16 (RNE), transposed [i][w][c]; batched loads
    float4 A0[6], A1[6];
#pragma unroll
    for (int q = 0; q < 6; ++q) {
        int it = tid + q*256;
        int wq = it & 15, c2 = (it >> 4) & 31, i = it >> 9;
        const float* p = x + (((size_t)(b*IC + c2*2))*64 + (oh + i))*64 + wq*4;
        A0[q] = *(const float4*)p;
        A1[q] = *(const float4*)(p + 4096);
    }
#pragma unroll
    for (int q = 0; q < 6; ++q) {
        int it = tid + q*256;
        int wq = it & 15, c2 = (it >> 4) & 31, i = it >> 9;
        int c = c2*2, w0 = wq*4;
        float f0[4] = {A0[q].x, A0[q].y, A0[q].z, A0[q].w};
        float f1[4] = {A1[q].x, A1[q].y, A1[q].z, A1[q].w};
#pragma unroll
        for (int jj = 0; jj < 4; ++jj) {
            int w = w0 + jj;
            unsigned u0 = __float_as_uint(f0[jj]);
            unsigned u1 = __float_as_uint(f1[jj]);
            unsigned r0 = u0 + 0x7FFFu + ((u0 >> 16) & 1u);   // RNE in high 16
            unsigned r1 = u1 + 0x7FFFu + ((u1 >> 16) & 1u);
            unsigned hi = packhi(r1, r0);
            int e = (i*66 + w)*64 + c;
            int widx = (e ^ SWZ(w)) >> 1;      // uint index, swizzled
            ((unsigned*)xh)[widx] = hi;
        }
    }
    __syncthreads();

    const int lane = tid & 63, wv = tid >> 6;
    const int l15 = lane & 15, lg = lane >> 4;
    const int kbase = wv*32;

    f32x4 acc[2][4];
#pragma unroll
    for (int kf = 0; kf < 2; ++kf)
#pragma unroll
        for (int nf = 0; nf < 4; ++nf)
            acc[kf][nf] = (f32x4){0.f,0.f,0.f,0.f};

    // A-frag prefetch ring, depth 2 (burst layout, 16 lanes contiguous).
    bf16x8 pah[3][2];
#pragma unroll
    for (int ps = 0; ps < 2; ++ps)
#pragma unroll
        for (int kf = 0; kf < 2; ++kf) {
            int k = kbase + kf*16 + l15;
            pah[ps][kf] = *(const bf16x8*)(wH + ((size_t)(ps*4 + lg)*128 + k)*8);
        }

    __builtin_amdgcn_s_setprio(1);
#pragma unroll
    for (int s = 0; s < 18; ++s) {
        const int ij = s >> 1, ch = s & 1;
        const int i = ij / 3, j = ij % 3;
        const int cur = s % 3;
        if (s + 2 < 18) {
            const int nxt = (s + 2) % 3;
#pragma unroll
            for (int kf = 0; kf < 2; ++kf) {
                int k = kbase + kf*16 + l15;
                pah[nxt][kf] = *(const bf16x8*)(wH + ((size_t)((s+2)*4 + lg)*128 + k)*8);
            }
        }
#pragma unroll
        for (int nf = 0; nf < 4; ++nf) {
            int w = nf*16 + l15 + j;
            int e = (i*66 + w)*64 + ch*32 + lg*8;
            int si = e ^ SWZ(w);
            bf16x8 bh = *(const bf16x8*)(xh + si);
#pragma unroll
            for (int kf = 0; kf < 2; ++kf)
                acc[kf][nf] = __builtin_amdgcn_mfma_f32_16x16x32_bf16(pah[cur][kf], bh, acc[kf][nf], 0, 0, 0);
        }
    }
    __builtin_amdgcn_s_setprio(0);

    // all xh reads done -> alias reduction arrays into xh
    __syncthreads();
    float* redv = (float*)xh;           // [4][64]
    int*   redi = ((int*)xh) + 256;     // [4][64]

    // bias + store y + argmax (C/D: row=lg*4+r, col=l15 [m89])
#pragma unroll
    for (int nf = 0; nf < 4; ++nf) {
        int n = nf*16 + l15;
        float vm = -3.4e38f; int im = 0;
#pragma unroll
        for (int kf = 0; kf < 2; ++kf)
#pragma unroll
            for (int r = 0; r < 4; ++r) {
                int k = kbase + kf*16 + lg*4 + r;
                float v2 = acc[kf][nf][r] + biasL[k];
                if (n < OHW) y[(((size_t)b*OC + k)*OHW + oh)*OHW + n] = v2;
                if (v2 > vm) { vm = v2; im = k; }      // ascending k, strict >
            }
        {
            float ov = __shfl_xor(vm, 16); int oi = __shfl_xor(im, 16);
            if (ov > vm || (ov == vm && oi < im)) { vm = ov; im = oi; }
            ov = __shfl_xor(vm, 32); oi = __shfl_xor(im, 32);
            if (ov > vm || (ov == vm && oi < im)) { vm = ov; im = oi; }
        }
        if (lg == 0) { redv[wv*64 + n] = vm; redi[wv*64 + n] = im; }
    }
    __syncthreads();
    if (tid < OHW) {
        float bv = redv[tid]; int bi = redi[tid];
#pragma unroll
        for (int wvv = 1; wvv < 4; ++wvv) {
            float v2 = redv[wvv*64 + tid]; int i2 = redi[wvv*64 + tid];
            if (v2 > bv || (v2 == bv && i2 < bi)) { bv = v2; bi = i2; }
        }
        winners[(size_t)b*LOCS + oh*OHW + tid] = bi;
    }
}

// ---------------- K3: Hebbian via one-hot-mask MFMA, c-quarter partials ---
__global__ __launch_bounds__(512, 4) void hebb_kernel(
    const float* __restrict__ x, const int* __restrict__ winners,
    unsigned short* __restrict__ part, int G)
{
    __shared__ short xR[16*10*72];   // [cLocal][row(10)][72], bf16; 23040 B
    __shared__ int winL[8*64];       // 2048 B

    const int bid = blockIdx.x;
    const int q = bid & 3, g = bid >> 2;
    const int tid = threadIdx.x;
    const int lane = tid & 63, wv = tid >> 6;
    const int l15 = lane & 15, lg = lane >> 4;
    const int myk = wv*16 + l15;

    int off0[3];
#pragma unroll
    for (int nf = 0; nf < 3; ++nf) {
        int npL = nf*16 + l15;           // 0..47 local = cLocal*3+i
        int cL = npL / 3, i = npL % 3;
        off0[nf] = (cL*10 + i)*72;
    }

    f32x4 acc[3][3];
#pragma unroll
    for (int j = 0; j < 3; ++j)
#pragma unroll
        for (int nf = 0; nf < 3; ++nf)
            acc[j][nf] = (f32x4){0.f,0.f,0.f,0.f};

    for (int t = g; t < 256; t += G) {
        const int b = t >> 3, sub = t & 7;
        const int oh0 = sub*8;
        const int NR = (sub == 7) ? 6 : 8;
        const int rows = NR + 2;

        __syncthreads();
        for (int it = tid; it < 16*rows*16; it += 512) {
            int wq2 = it & 15;
            int t2 = it >> 4;
            int r = t2 % rows, cL = t2 / rows;
            const float* p = x + (((size_t)(b*IC + q*16 + cL))*64 + (oh0 + r))*64 + wq2*4;
            float4 a = *(const float4*)p;
            unsigned u0 = packhi(__float_as_uint(a.y), __float_as_uint(a.x));
            unsigned u1 = packhi(__float_as_uint(a.w), __float_as_uint(a.z));
            int e = (cL*10 + r)*72 + wq2*4;
            ((unsigned*)xR)[e >> 1]       = u0;
            ((unsigned*)xR)[(e >> 1) + 1] = u1;
        }
        for (int tt = tid; tt < NR*64; tt += 512) {
            int r = tt >> 6, ow = tt & 63;
            winL[tt] = (ow < OHW) ? winners[(size_t)b*LOCS + (oh0 + r)*OHW + ow] : -1;
        }
        __syncthreads();

        for (int r = 0; r < NR; ++r) {
#pragma unroll
            for (int h = 0; h < 2; ++h) {
                const int base = h*32 + lg*8;
                const int* wrow = &winL[r*64];
                int wreg[8];
                *(int4*)&wreg[0] = *(const int4*)&wrow[base];
                *(int4*)&wreg[4] = *(const int4*)&wrow[base + 4];
                const int wm1 = (base >= 1) ? wrow[base-1] : -1;
                const int wm2 = (base >= 2) ? wrow[base-2] : -1;
                union U8 { unsigned u[4]; bf16x8 v; };
                bf16x8 am[3];
#pragma unroll
                for (int j = 0; j < 3; ++j) {
                    U8 tmp;
#pragma unroll
                    for (int p2 = 0; p2 < 4; ++p2) {
                        int t0 = p2*2, t1 = t0 + 1;
                        int s0 = (t0 >= j) ? wreg[t0-j] : ((j - t0 == 1) ? wm1 : wm2);
                        int s1 = (t1 >= j) ? wreg[t1-j] : ((j - t1 == 1) ? wm1 : wm2);
                        tmp.u[p2] = ((s0 == myk) ? 0x3F80u : 0u)
                                  | (((s1 == myk) ? 0x3F80u : 0u) << 16);
                    }
                    am[j] = tmp.v;
                }
#pragma unroll
                for (int nf = 0; nf < 3; ++nf) {
                    const bf16x8 bb = *(const bf16x8*)&xR[off0[nf] + r*72 + base];
#pragma unroll
                    for (int j = 0; j < 3; ++j)
                        acc[j][nf] = __builtin_amdgcn_mfma_f32_16x16x32_bf16(am[j], bb, acc[j][nf], 0, 0, 0);
                }
            }
        }
    }

    // one bf16 partial write per block: part[bid][rowL(144)][k(128)]
    unsigned short* dst = part + (size_t)bid*(144*128);
#pragma unroll
    for (int j = 0; j < 3; ++j)
#pragma unroll
        for (int nf = 0; nf < 3; ++nf) {
            int npL = nf*16 + l15;
            int rowL = npL*3 + j;               // 0..143
            int kc   = wv*16 + lg*4;
            ushort4 o;
            o.x = f2bf(acc[j][nf][0]); o.y = f2bf(acc[j][nf][1]);
            o.z = f2bf(acc[j][nf][2]); o.w = f2bf(acc[j][nf][3]);
            *(ushort4*)(dst + rowL*128 + kc) = o;
        }
}

// ---------------- K4: reduce bf16 partials + scale + transpose ------------
__global__ __launch_bounds__(256) void final_kernel(const unsigned short* __restrict__ part,
                                                    float* __restrict__ upd, int G) {
    int t = blockIdx.x*256 + threadIdx.x;      // 73728 threads: t = row*128 + k
    int k = t & 127, row = t >> 7;             // row = c*9+i*3+j (576)
    int q = row / 144;                         // c-quarter
    int rowL = row - q*144;
    float s = 0.f;
    for (int g = 0; g < G; ++g)
        s += bf2f(part[((size_t)(g*4 + q))*(144*128) + rowL*128 + k]);
    upd[(size_t)k*576 + row] = s * (1.0f/123008.0f);
}

extern "C" void kernel_launch(void* const* d_in, const int* in_sizes, int n_in,
                              void* d_out, int out_size, void* d_ws, size_t ws_size,
                              hipStream_t stream) {
    const float* x    = (const float*)d_in[0];
    const float* w    = (const float*)d_in[1];
    const float* bias = (const float*)d_in[2];
    float* out = (float*)d_out;
    float* y   = out;
    float* upd = out + Y_SIZE;

    // ws: wH 147456 | winners 492032 | partials 4G*36864 B
    const size_t fixed = 147456 + 492032;   // 639488
    short* wHs     = (short*)d_ws;
    int*   winners = (int*)((char*)d_ws + 147456);
    unsigned short* part = (unsigned short*)((char*)d_ws + fixed);

    size_t avail = (ws_size > fixed) ? (ws_size - fixed) : 0;
    int G = (int)(avail / (4*36864));
    if (G > 256) G = 256;
    if (G < 1)   G = 1;

    wnorm_kernel<<<OC, IC, 0, stream>>>(w, wHs);
    conv_kernel<<<OHW*BATCH, 256, 0, stream>>>(x, wHs, bias, y, winners);
    hebb_kernel<<<4*G, 512, 0, stream>>>(x, winners, part, G);
    final_kernel<<<UPD_SIZE/256, 256, 0, stream>>>(part, upd, G);
}

// Round 16
// 95.665 us; speedup vs baseline: 1.4046x; 1.4046x over previous
//
#include <hip/hip_runtime.h>
#include <math.h>

typedef __attribute__((ext_vector_type(8))) short bf16x8;
typedef __attribute__((ext_vector_type(4))) float f32x4;

#define IC 64
#define OC 128
#define OHW 62
#define LOCS (OHW*OHW)          /* 3844 */
#define BATCH 32
#define Y_SIZE (BATCH*OC*LOCS)  /* 15740928 */
#define UPD_SIZE (OC*IC*9)      /* 73728 */

#define SWZ(w) (((w) & 7) << 3)

__device__ __forceinline__ unsigned short f2bf(float f) {
    unsigned u = __float_as_uint(f);
    unsigned r = (u + 0x7FFFu + ((u >> 16) & 1u)) >> 16;   // RNE
    return (unsigned short)r;
}
__device__ __forceinline__ float bf2f(unsigned short h) {
    return __uint_as_float(((unsigned)h) << 16);
}
// pack hi16(u1)<<16 | hi16(u0) in ONE v_perm
__device__ __forceinline__ unsigned packhi(unsigned u1, unsigned u0) {
    return __builtin_amdgcn_perm(u1, u0, 0x07060302u);
}

// ---------------- K1: weight norm -> wH burst layout [s=ij*2+ch][lg][k][8c]
__global__ void wnorm_kernel(const float* __restrict__ w, short* __restrict__ wH) {
    int k = blockIdx.x;      // 0..127
    int c = threadIdx.x;     // 0..63
    const float* wp = w + ((size_t)k*IC + c)*9;
    float v[9]; float s = 0.f;
#pragma unroll
    for (int t = 0; t < 9; ++t) { v[t] = wp[t]; s += v[t]*v[t]; }
#pragma unroll
    for (int off = 32; off > 0; off >>= 1) s += __shfl_xor(s, off);
    float nrm = sqrtf(s);
    if (nrm == 0.f) nrm = 1.f;
    float inv = 1.f / nrm;
    const int ch = c >> 5, lg = (c >> 3) & 3, pos = c & 7;
#pragma unroll
    for (int t = 0; t < 9; ++t) {
        size_t off = ((size_t)((t*2 + ch)*4 + lg)*128 + k)*8 + pos;
        wH[off] = (short)f2bf(v[t]*inv);
    }
}

// ---------------- K2: conv via 1-term bf16 MFMA + bias + argmax -----------
// 1-D grid 1984 = 8*248, XCD-clustered: xcd = l&7 owns 4 complete batches.
__global__ __launch_bounds__(256, 6) void conv_kernel(
    const float* __restrict__ x, const short* __restrict__ wH,
    const float* __restrict__ bias, float* __restrict__ y,
    int* __restrict__ winners)
{
    __shared__ short xh[3*66*64];    // [i][w(66)][c], bf16 RNE, swizzled; 25344 B
    __shared__ float biasL[OC];

    const int l = blockIdx.x;
    const int v = (l & 7)*248 + (l >> 3);   // bijective: 1984 = 8*248
    const int b = v / OHW;
    const int oh = v - b*OHW;
    const int tid = threadIdx.x;
    if (tid < OC) biasL[tid] = bias[tid];

    // stage x[b,:,oh..oh+2,:] -> bf16 (RNE), transposed [i][w][c]; batched loads
    float4 A0[6], A1[6];
#pragma unroll
    for (int q = 0; q < 6; ++q) {
        int it = tid + q*256;
        int wq = it & 15, c2 = (it >> 4) & 31, i = it >> 9;
        const float* p = x + (((size_t)(b*IC + c2*2))*64 + (oh + i))*64 + wq*4;
        A0[q] = *(const float4*)p;
        A1[q] = *(const float4*)(p + 4096);
    }
#pragma unroll
    for (int q = 0; q < 6; ++q) {
        int it = tid + q*256;
        int wq = it & 15, c2 = (it >> 4) & 31, i = it >> 9;
        int c = c2*2, w0 = wq*4;
        float f0[4] = {A0[q].x, A0[q].y, A0[q].z, A0[q].w};
        float f1[4] = {A1[q].x, A1[q].y, A1[q].z, A1[q].w};
#pragma unroll
        for (int jj = 0; jj < 4; ++jj) {
            int w = w0 + jj;
            unsigned u0 = __float_as_uint(f0[jj]);
            unsigned u1 = __float_as_uint(f1[jj]);
            unsigned r0 = u0 + 0x7FFFu + ((u0 >> 16) & 1u);   // RNE in high 16
            unsigned r1 = u1 + 0x7FFFu + ((u1 >> 16) & 1u);
            unsigned hi = packhi(r1, r0);
            int e = (i*66 + w)*64 + c;
            int widx = (e ^ SWZ(w)) >> 1;      // uint index, swizzled
            ((unsigned*)xh)[widx] = hi;
        }
    }
    __syncthreads();

    const int lane = tid & 63, wv = tid >> 6;
    const int l15 = lane & 15, lg = lane >> 4;
    const int kbase = wv*32;

    f32x4 acc[2][4];
#pragma unroll
    for (int kf = 0; kf < 2; ++kf)
#pragma unroll
        for (int nf = 0; nf < 4; ++nf)
            acc[kf][nf] = (f32x4){0.f,0.f,0.f,0.f};

    // A-frag prefetch ring, depth 2 (burst layout, 16 lanes contiguous).
    bf16x8 pah[3][2];
#pragma unroll
    for (int ps = 0; ps < 2; ++ps)
#pragma unroll
        for (int kf = 0; kf < 2; ++kf) {
            int k = kbase + kf*16 + l15;
            pah[ps][kf] = *(const bf16x8*)(wH + ((size_t)(ps*4 + lg)*128 + k)*8);
        }

    __builtin_amdgcn_s_setprio(1);
#pragma unroll
    for (int s = 0; s < 18; ++s) {
        const int ij = s >> 1, ch = s & 1;
        const int i = ij / 3, j = ij % 3;
        const int cur = s % 3;
        if (s + 2 < 18) {
            const int nxt = (s + 2) % 3;
#pragma unroll
            for (int kf = 0; kf < 2; ++kf) {
                int k = kbase + kf*16 + l15;
                pah[nxt][kf] = *(const bf16x8*)(wH + ((size_t)((s+2)*4 + lg)*128 + k)*8);
            }
        }
#pragma unroll
        for (int nf = 0; nf < 4; ++nf) {
            int w = nf*16 + l15 + j;
            int e = (i*66 + w)*64 + ch*32 + lg*8;
            int si = e ^ SWZ(w);
            bf16x8 bh = *(const bf16x8*)(xh + si);
#pragma unroll
            for (int kf = 0; kf < 2; ++kf)
                acc[kf][nf] = __builtin_amdgcn_mfma_f32_16x16x32_bf16(pah[cur][kf], bh, acc[kf][nf], 0, 0, 0);
        }
    }
    __builtin_amdgcn_s_setprio(0);

    // all xh reads done -> alias reduction arrays into xh
    __syncthreads();
    float* redv = (float*)xh;           // [4][64]
    int*   redi = ((int*)xh) + 256;     // [4][64]

    // bias + store y + argmax (C/D: row=lg*4+r, col=l15 [m89])
#pragma unroll
    for (int nf = 0; nf < 4; ++nf) {
        int n = nf*16 + l15;
        float vm = -3.4e38f; int im = 0;
#pragma unroll
        for (int kf = 0; kf < 2; ++kf)
#pragma unroll
            for (int r = 0; r < 4; ++r) {
                int k = kbase + kf*16 + lg*4 + r;
                float v2 = acc[kf][nf][r] + biasL[k];
                if (n < OHW) y[(((size_t)b*OC + k)*OHW + oh)*OHW + n] = v2;
                if (v2 > vm) { vm = v2; im = k; }      // ascending k, strict >
            }
        {
            float ov = __shfl_xor(vm, 16); int oi = __shfl_xor(im, 16);
            if (ov > vm || (ov == vm && oi < im)) { vm = ov; im = oi; }
            ov = __shfl_xor(vm, 32); oi = __shfl_xor(im, 32);
            if (ov > vm || (ov == vm && oi < im)) { vm = ov; im = oi; }
        }
        if (lg == 0) { redv[wv*64 + n] = vm; redi[wv*64 + n] = im; }
    }
    __syncthreads();
    if (tid < OHW) {
        float bv = redv[tid]; int bi = redi[tid];
#pragma unroll
        for (int wvv = 1; wvv < 4; ++wvv) {
            float v2 = redv[wvv*64 + tid]; int i2 = redi[wvv*64 + tid];
            if (v2 > bv || (v2 == bv && i2 < bi)) { bv = v2; bi = i2; }
        }
        winners[(size_t)b*LOCS + oh*OHW + tid] = bi;
    }
}

// ---------------- K3: Hebbian via one-hot-mask MFMA, c-quarter partials ---
__global__ __launch_bounds__(512, 4) void hebb_kernel(
    const float* __restrict__ x, const int* __restrict__ winners,
    unsigned short* __restrict__ part, int G)
{
    __shared__ short xR[16*10*72];   // [cLocal][row(10)][72], bf16; 23040 B
    __shared__ int winL[8*64];       // 2048 B

    const int bid = blockIdx.x;
    const int q = bid & 3, g = bid >> 2;
    const int tid = threadIdx.x;
    const int lane = tid & 63, wv = tid >> 6;
    const int l15 = lane & 15, lg = lane >> 4;
    const int myk = wv*16 + l15;

    int off0[3];
#pragma unroll
    for (int nf = 0; nf < 3; ++nf) {
        int npL = nf*16 + l15;           // 0..47 local = cLocal*3+i
        int cL = npL / 3, i = npL % 3;
        off0[nf] = (cL*10 + i)*72;
    }

    f32x4 acc[3][3];
#pragma unroll
    for (int j = 0; j < 3; ++j)
#pragma unroll
        for (int nf = 0; nf < 3; ++nf)
            acc[j][nf] = (f32x4){0.f,0.f,0.f,0.f};

    for (int t = g; t < 256; t += G) {
        const int b = t >> 3, sub = t & 7;
        const int oh0 = sub*8;
        const int NR = (sub == 7) ? 6 : 8;
        const int rows = NR + 2;

        __syncthreads();
        for (int it = tid; it < 16*rows*16; it += 512) {
            int wq2 = it & 15;
            int t2 = it >> 4;
            int r = t2 % rows, cL = t2 / rows;
            const float* p = x + (((size_t)(b*IC + q*16 + cL))*64 + (oh0 + r))*64 + wq2*4;
            float4 a = *(const float4*)p;
            unsigned u0 = packhi(__float_as_uint(a.y), __float_as_uint(a.x));
            unsigned u1 = packhi(__float_as_uint(a.w), __float_as_uint(a.z));
            int e = (cL*10 + r)*72 + wq2*4;
            ((unsigned*)xR)[e >> 1]       = u0;
            ((unsigned*)xR)[(e >> 1) + 1] = u1;
        }
        for (int tt = tid; tt < NR*64; tt += 512) {
            int r = tt >> 6, ow = tt & 63;
            winL[tt] = (ow < OHW) ? winners[(size_t)b*LOCS + (oh0 + r)*OHW + ow] : -1;
        }
        __syncthreads();

        for (int r = 0; r < NR; ++r) {
#pragma unroll
            for (int h = 0; h < 2; ++h) {
                const int base = h*32 + lg*8;
                const int* wrow = &winL[r*64];
                int wreg[8];
                *(int4*)&wreg[0] = *(const int4*)&wrow[base];
                *(int4*)&wreg[4] = *(const int4*)&wrow[base + 4];
                const int wm1 = (base >= 1) ? wrow[base-1] : -1;
                const int wm2 = (base >= 2) ? wrow[base-2] : -1;
                union U8 { unsigned u[4]; bf16x8 v; };
                bf16x8 am[3];
#pragma unroll
                for (int j = 0; j < 3; ++j) {
                    U8 tmp;
#pragma unroll
                    for (int p2 = 0; p2 < 4; ++p2) {
                        int t0 = p2*2, t1 = t0 + 1;
                        int s0 = (t0 >= j) ? wreg[t0-j] : ((j - t0 == 1) ? wm1 : wm2);
                        int s1 = (t1 >= j) ? wreg[t1-j] : ((j - t1 == 1) ? wm1 : wm2);
                        tmp.u[p2] = ((s0 == myk) ? 0x3F80u : 0u)
                                  | (((s1 == myk) ? 0x3F80u : 0u) << 16);
                    }
                    am[j] = tmp.v;
                }
#pragma unroll
                for (int nf = 0; nf < 3; ++nf) {
                    const bf16x8 bb = *(const bf16x8*)&xR[off0[nf] + r*72 + base];
#pragma unroll
                    for (int j = 0; j < 3; ++j)
                        acc[j][nf] = __builtin_amdgcn_mfma_f32_16x16x32_bf16(am[j], bb, acc[j][nf], 0, 0, 0);
                }
            }
        }
    }

    // one bf16 partial write per block: part[bid][rowL(144)][k(128)]
    unsigned short* dst = part + (size_t)bid*(144*128);
#pragma unroll
    for (int j = 0; j < 3; ++j)
#pragma unroll
        for (int nf = 0; nf < 3; ++nf) {
            int npL = nf*16 + l15;
            int rowL = npL*3 + j;               // 0..143
            int kc   = wv*16 + lg*4;
            ushort4 o;
            o.x = f2bf(acc[j][nf][0]); o.y = f2bf(acc[j][nf][1]);
            o.z = f2bf(acc[j][nf][2]); o.w = f2bf(acc[j][nf][3]);
            *(ushort4*)(dst + rowL*128 + kc) = o;
        }
}

// ---------------- K4a: stage-A reduction: 16 partials per thread ----------
// grid 288*NS; block (ob, ns): each thread sums g in [ns*16, min(G,ns*16+16))
__global__ __launch_bounds__(256) void final1_kernel(const unsigned short* __restrict__ part,
                                                     float* __restrict__ tmp, int G, int NS) {
    int bid = blockIdx.x;
    int ob = bid % 288, ns = bid / 288;
    int t = ob*256 + threadIdx.x;              // t = row*128 + k
    int k = t & 127, row = t >> 7;
    int q = row / 144;
    int rowL = row - q*144;
    int g0 = ns*16, g1 = g0 + 16; if (g1 > G) g1 = G;
    float s = 0.f;
    for (int g = g0; g < g1; ++g)
        s += bf2f(part[((size_t)(g*4 + q))*(144*128) + rowL*128 + k]);
    tmp[(size_t)ns*UPD_SIZE + t] = s;
}

// ---------------- K4b: stage-B: sum NS floats + scale + transpose ---------
__global__ __launch_bounds__(256) void final2_kernel(const float* __restrict__ tmp,
                                                     float* __restrict__ upd, int NS) {
    int t = blockIdx.x*256 + threadIdx.x;      // t = row*128 + k
    int k = t & 127, row = t >> 7;
    float s = 0.f;
    for (int ns = 0; ns < NS; ++ns)
        s += tmp[(size_t)ns*UPD_SIZE + t];
    upd[(size_t)k*576 + row] = s * (1.0f/123008.0f);
}

extern "C" void kernel_launch(void* const* d_in, const int* in_sizes, int n_in,
                              void* d_out, int out_size, void* d_ws, size_t ws_size,
                              hipStream_t stream) {
    const float* x    = (const float*)d_in[0];
    const float* w    = (const float*)d_in[1];
    const float* bias = (const float*)d_in[2];
    float* out = (float*)d_out;
    float* y   = out;
    float* upd = out + Y_SIZE;

    // ws: wH 147456 | winners 492032 | partials 4G*36864 | tmp NS*294912
    const size_t fixed = 147456 + 492032;   // 639488
    short* wHs     = (short*)d_ws;
    int*   winners = (int*)((char*)d_ws + 147456);

    size_t avail = (ws_size > fixed) ? (ws_size - fixed) : 0;
    int G = 256;
    while (G > 1) {
        size_t need = (size_t)4*G*36864 + (size_t)((G + 15)/16)*294912;
        if (need <= avail) break;
        G >>= 1;
    }
    int NS = (G + 15)/16;

    unsigned short* part = (unsigned short*)((char*)d_ws + fixed);
    float* tmp = (float*)((char*)d_ws + fixed + (size_t)4*G*36864);

    wnorm_kernel<<<OC, IC, 0, stream>>>(w, wHs);
    conv_kernel<<<OHW*BATCH, 256, 0, stream>>>(x, wHs, bias, y, winners);
    hebb_kernel<<<4*G, 512, 0, stream>>>(x, winners, part, G);
    final1_kernel<<<288*NS, 256, 0, stream>>>(part, tmp, G, NS);
    final2_kernel<<<288, 256, 0, stream>>>(tmp, upd, NS);
}

// Round 17
// 90.199 us; speedup vs baseline: 1.4897x; 1.0606x over previous
//
#include <hip/hip_runtime.h>
#include <math.h>

typedef __attribute__((ext_vector_type(8))) short bf16x8;
typedef __attribute__((ext_vector_type(4))) float f32x4;

#define IC 64
#define OC 128
#define OHW 62
#define LOCS (OHW*OHW)          /* 3844 */
#define BATCH 32
#define Y_SIZE (BATCH*OC*LOCS)  /* 15740928 */
#define UPD_SIZE (OC*IC*9)      /* 73728 */

#define SWZ(w) (((w) & 7) << 3)

__device__ __forceinline__ unsigned short f2bf(float f) {
    unsigned u = __float_as_uint(f);
    unsigned r = (u + 0x7FFFu + ((u >> 16) & 1u)) >> 16;   // RNE
    return (unsigned short)r;
}
__device__ __forceinline__ float bf2f(unsigned short h) {
    return __uint_as_float(((unsigned)h) << 16);
}
// pack hi16(u1)<<16 | hi16(u0) in ONE v_perm
__device__ __forceinline__ unsigned packhi(unsigned u1, unsigned u0) {
    return __builtin_amdgcn_perm(u1, u0, 0x07060302u);
}

// ---------------- K1: weight norm -> wH burst layout [s=ij*2+ch][lg][k][8c]
__global__ void wnorm_kernel(const float* __restrict__ w, short* __restrict__ wH) {
    int k = blockIdx.x;      // 0..127
    int c = threadIdx.x;     // 0..63
    const float* wp = w + ((size_t)k*IC + c)*9;
    float v[9]; float s = 0.f;
#pragma unroll
    for (int t = 0; t < 9; ++t) { v[t] = wp[t]; s += v[t]*v[t]; }
#pragma unroll
    for (int off = 32; off > 0; off >>= 1) s += __shfl_xor(s, off);
    float nrm = sqrtf(s);
    if (nrm == 0.f) nrm = 1.f;
    float inv = 1.f / nrm;
    const int ch = c >> 5, lg = (c >> 3) & 3, pos = c & 7;
#pragma unroll
    for (int t = 0; t < 9; ++t) {
        size_t off = ((size_t)((t*2 + ch)*4 + lg)*128 + k)*8 + pos;
        wH[off] = (short)f2bf(v[t]*inv);
    }
}

// ---------------- K2: conv via 1-term bf16 MFMA + bias + argmax -----------
// 1-D grid 1984 = 8*248, XCD-clustered. 4 waves: wv = (nhalf<<1)|khalf;
// wave tile 64k x 32n -> each LDS B-read feeds 4 MFMAs (halved LDS traffic).
__global__ __launch_bounds__(256, 4) void conv_kernel(
    const float* __restrict__ x, const short* __restrict__ wH,
    const float* __restrict__ bias, float* __restrict__ y,
    int* __restrict__ winners)
{
    __shared__ short xh[3*66*64];    // [i][w(66)][c], bf16 RNE, swizzled; 25344 B
    __shared__ float biasL[OC];

    const int l = blockIdx.x;
    const int v = (l & 7)*248 + (l >> 3);   // bijective: 1984 = 8*248
    const int b = v / OHW;
    const int oh = v - b*OHW;
    const int tid = threadIdx.x;
    if (tid < OC) biasL[tid] = bias[tid];

    // stage x[b,:,oh..oh+2,:] -> bf16 (RNE), transposed [i][w][c]; batched loads
    float4 A0[6], A1[6];
#pragma unroll
    for (int q = 0; q < 6; ++q) {
        int it = tid + q*256;
        int wq = it & 15, c2 = (it >> 4) & 31, i = it >> 9;
        const float* p = x + (((size_t)(b*IC + c2*2))*64 + (oh + i))*64 + wq*4;
        A0[q] = *(const float4*)p;
        A1[q] = *(const float4*)(p + 4096);
    }
#pragma unroll
    for (int q = 0; q < 6; ++q) {
        int it = tid + q*256;
        int wq = it & 15, c2 = (it >> 4) & 31, i = it >> 9;
        int c = c2*2, w0 = wq*4;
        float f0[4] = {A0[q].x, A0[q].y, A0[q].z, A0[q].w};
        float f1[4] = {A1[q].x, A1[q].y, A1[q].z, A1[q].w};
#pragma unroll
        for (int jj = 0; jj < 4; ++jj) {
            int w = w0 + jj;
            unsigned u0 = __float_as_uint(f0[jj]);
            unsigned u1 = __float_as_uint(f1[jj]);
            unsigned r0 = u0 + 0x7FFFu + ((u0 >> 16) & 1u);   // RNE in high 16
            unsigned r1 = u1 + 0x7FFFu + ((u1 >> 16) & 1u);
            unsigned hi = packhi(r1, r0);
            int e = (i*66 + w)*64 + c;
            int widx = (e ^ SWZ(w)) >> 1;      // uint index, swizzled
            ((unsigned*)xh)[widx] = hi;
        }
    }
    __syncthreads();

    const int lane = tid & 63, wv = tid >> 6;
    const int l15 = lane & 15, lg = lane >> 4;
    const int khalf = wv & 1, nhalf = wv >> 1;
    const int kbase = khalf*64, nbase = nhalf*32;

    f32x4 acc[4][2];
#pragma unroll
    for (int kf = 0; kf < 4; ++kf)
#pragma unroll
        for (int nf = 0; nf < 2; ++nf)
            acc[kf][nf] = (f32x4){0.f,0.f,0.f,0.f};

    // A-frag prefetch ring, depth 2 (burst layout, 16 lanes contiguous).
    bf16x8 pah[3][4];
#pragma unroll
    for (int ps = 0; ps < 2; ++ps)
#pragma unroll
        for (int kf = 0; kf < 4; ++kf) {
            int k = kbase + kf*16 + l15;
            pah[ps][kf] = *(const bf16x8*)(wH + ((size_t)(ps*4 + lg)*128 + k)*8);
        }

    __builtin_amdgcn_s_setprio(1);
#pragma unroll
    for (int s = 0; s < 18; ++s) {
        const int ij = s >> 1, ch = s & 1;
        const int i = ij / 3, j = ij % 3;
        const int cur = s % 3;
        if (s + 2 < 18) {
            const int nxt = (s + 2) % 3;
#pragma unroll
            for (int kf = 0; kf < 4; ++kf) {
                int k = kbase + kf*16 + l15;
                pah[nxt][kf] = *(const bf16x8*)(wH + ((size_t)((s+2)*4 + lg)*128 + k)*8);
            }
        }
#pragma unroll
        for (int nf = 0; nf < 2; ++nf) {
            int w = nbase + nf*16 + l15 + j;
            int e = (i*66 + w)*64 + ch*32 + lg*8;
            int si = e ^ SWZ(w);
            bf16x8 bh = *(const bf16x8*)(xh + si);
#pragma unroll
            for (int kf = 0; kf < 4; ++kf)
                acc[kf][nf] = __builtin_amdgcn_mfma_f32_16x16x32_bf16(pah[cur][kf], bh, acc[kf][nf], 0, 0, 0);
        }
    }
    __builtin_amdgcn_s_setprio(0);

    // all xh reads done -> alias reduction arrays into xh
    __syncthreads();
    float* redv = (float*)xh;           // [4][64]
    int*   redi = ((int*)xh) + 256;     // [4][64]

    // bias + store y + argmax (C/D: row=lg*4+r, col=l15 [m89])
#pragma unroll
    for (int nf = 0; nf < 2; ++nf) {
        int n = nbase + nf*16 + l15;
        float vm = -3.4e38f; int im = 0;
#pragma unroll
        for (int kf = 0; kf < 4; ++kf)
#pragma unroll
            for (int r = 0; r < 4; ++r) {
                int k = kbase + kf*16 + lg*4 + r;
                float v2 = acc[kf][nf][r] + biasL[k];
                if (n < OHW) y[(((size_t)b*OC + k)*OHW + oh)*OHW + n] = v2;
                if (v2 > vm) { vm = v2; im = k; }      // ascending k, strict >
            }
        {
            float ov = __shfl_xor(vm, 16); int oi = __shfl_xor(im, 16);
            if (ov > vm || (ov == vm && oi < im)) { vm = ov; im = oi; }
            ov = __shfl_xor(vm, 32); oi = __shfl_xor(im, 32);
            if (ov > vm || (ov == vm && oi < im)) { vm = ov; im = oi; }
        }
        if (lg == 0) { redv[wv*64 + n] = vm; redi[wv*64 + n] = im; }
    }
    __syncthreads();
    if (tid < OHW) {
        int w0 = (tid >> 5)*2;              // waves {w0, w0+1} cover this n
        float bv = redv[w0*64 + tid]; int bi = redi[w0*64 + tid];
        float v2 = redv[(w0+1)*64 + tid]; int i2 = redi[(w0+1)*64 + tid];
        if (v2 > bv || (v2 == bv && i2 < bi)) { bv = v2; bi = i2; }
        winners[(size_t)b*LOCS + oh*OHW + tid] = bi;
    }
}

// ---------------- K3: Hebbian via one-hot-mask MFMA, c-quarter partials ---
__global__ __launch_bounds__(512, 4) void hebb_kernel(
    const float* __restrict__ x, const int* __restrict__ winners,
    unsigned short* __restrict__ part, int G)
{
    __shared__ short xR[16*10*72];   // [cLocal][row(10)][72], bf16; 23040 B
    __shared__ int winL[8*64];       // 2048 B

    const int bid = blockIdx.x;
    const int q = bid & 3, g = bid >> 2;
    const int tid = threadIdx.x;
    const int lane = tid & 63, wv = tid >> 6;
    const int l15 = lane & 15, lg = lane >> 4;
    const int myk = wv*16 + l15;

    int off0[3];
#pragma unroll
    for (int nf = 0; nf < 3; ++nf) {
        int npL = nf*16 + l15;           // 0..47 local = cLocal*3+i
        int cL = npL / 3, i = npL % 3;
        off0[nf] = (cL*10 + i)*72;
    }

    f32x4 acc[3][3];
#pragma unroll
    for (int j = 0; j < 3; ++j)
#pragma unroll
        for (int nf = 0; nf < 3; ++nf)
            acc[j][nf] = (f32x4){0.f,0.f,0.f,0.f};

    for (int t = g; t < 256; t += G) {
        const int b = t >> 3, sub = t & 7;
        const int oh0 = sub*8;
        const int NR = (sub == 7) ? 6 : 8;
        const int rows = NR + 2;
        const int cnt = rows >> 1;          // 5 (rows=10) or 4 (rows=8)

        __syncthreads();
        // batched staging: issue all loads first (predicated, static index)
        float4 A[5];
#pragma unroll
        for (int q2 = 0; q2 < 5; ++q2) {
            if (q2 < cnt) {
                int it = tid + q2*512;
                int wq2 = it & 15;
                int t2 = it >> 4;
                int r = t2 % rows, cL = t2 / rows;
                const float* p = x + (((size_t)(b*IC + q*16 + cL))*64 + (oh0 + r))*64 + wq2*4;
                A[q2] = *(const float4*)p;
            }
        }
        int wval = -1;
        const int haveW = tid < NR*64;
        if (haveW) {
            int r = tid >> 6, ow = tid & 63;
            wval = (ow < OHW) ? winners[(size_t)b*LOCS + (oh0 + r)*OHW + ow] : -1;
        }
#pragma unroll
        for (int q2 = 0; q2 < 5; ++q2) {
            if (q2 < cnt) {
                int it = tid + q2*512;
                int wq2 = it & 15;
                int t2 = it >> 4;
                int r = t2 % rows, cL = t2 / rows;
                unsigned u0 = packhi(__float_as_uint(A[q2].y), __float_as_uint(A[q2].x));
                unsigned u1 = packhi(__float_as_uint(A[q2].w), __float_as_uint(A[q2].z));
                int e = (cL*10 + r)*72 + wq2*4;
                ((unsigned*)xR)[e >> 1]       = u0;
                ((unsigned*)xR)[(e >> 1) + 1] = u1;
            }
        }
        if (haveW) winL[tid] = wval;
        __syncthreads();

        for (int r = 0; r < NR; ++r) {
#pragma unroll
            for (int h = 0; h < 2; ++h) {
                const int base = h*32 + lg*8;
                const int* wrow = &winL[r*64];
                int wreg[8];
                *(int4*)&wreg[0] = *(const int4*)&wrow[base];
                *(int4*)&wreg[4] = *(const int4*)&wrow[base + 4];
                const int wm1 = (base >= 1) ? wrow[base-1] : -1;
                const int wm2 = (base >= 2) ? wrow[base-2] : -1;
                union U8 { unsigned u[4]; bf16x8 v; };
                bf16x8 am[3];
#pragma unroll
                for (int j = 0; j < 3; ++j) {
                    U8 tmp;
#pragma unroll
                    for (int p2 = 0; p2 < 4; ++p2) {
                        int t0 = p2*2, t1 = t0 + 1;
                        int s0 = (t0 >= j) ? wreg[t0-j] : ((j - t0 == 1) ? wm1 : wm2);
                        int s1 = (t1 >= j) ? wreg[t1-j] : ((j - t1 == 1) ? wm1 : wm2);
                        tmp.u[p2] = ((s0 == myk) ? 0x3F80u : 0u)
                                  | (((s1 == myk) ? 0x3F80u : 0u) << 16);
                    }
                    am[j] = tmp.v;
                }
#pragma unroll
                for (int nf = 0; nf < 3; ++nf) {
                    const bf16x8 bb = *(const bf16x8*)&xR[off0[nf] + r*72 + base];
#pragma unroll
                    for (int j = 0; j < 3; ++j)
                        acc[j][nf] = __builtin_amdgcn_mfma_f32_16x16x32_bf16(am[j], bb, acc[j][nf], 0, 0, 0);
                }
            }
        }
    }

    // one bf16 partial write per block: part[bid][rowL(144)][k(128)]
    unsigned short* dst = part + (size_t)bid*(144*128);
#pragma unroll
    for (int j = 0; j < 3; ++j)
#pragma unroll
        for (int nf = 0; nf < 3; ++nf) {
            int npL = nf*16 + l15;
            int rowL = npL*3 + j;               // 0..143
            int kc   = wv*16 + lg*4;
            ushort4 o;
            o.x = f2bf(acc[j][nf][0]); o.y = f2bf(acc[j][nf][1]);
            o.z = f2bf(acc[j][nf][2]); o.w = f2bf(acc[j][nf][3]);
            *(ushort4*)(dst + rowL*128 + kc) = o;
        }
}

// ---------------- K4a: stage-A reduction: 16 partials per thread ----------
__global__ __launch_bounds__(256) void final1_kernel(const unsigned short* __restrict__ part,
                                                     float* __restrict__ tmp, int G, int NS) {
    int bid = blockIdx.x;
    int ob = bid % 288, ns = bid / 288;
    int t = ob*256 + threadIdx.x;              // t = row*128 + k
    int k = t & 127, row = t >> 7;
    int q = row / 144;
    int rowL = row - q*144;
    int g0 = ns*16, g1 = g0 + 16; if (g1 > G) g1 = G;
    float s = 0.f;
#pragma unroll 4
    for (int g = g0; g < g1; ++g)
        s += bf2f(part[((size_t)(g*4 + q))*(144*128) + rowL*128 + k]);
    tmp[(size_t)ns*UPD_SIZE + t] = s;
}

// ---------------- K4b: stage-B: sum NS floats + scale + transpose ---------
__global__ __launch_bounds__(256) void final2_kernel(const float* __restrict__ tmp,
                                                     float* __restrict__ upd, int NS) {
    int t = blockIdx.x*256 + threadIdx.x;      // t = row*128 + k
    int k = t & 127, row = t >> 7;
    float s = 0.f;
    for (int ns = 0; ns < NS; ++ns)
        s += tmp[(size_t)ns*UPD_SIZE + t];
    upd[(size_t)k*576 + row] = s * (1.0f/123008.0f);
}

extern "C" void kernel_launch(void* const* d_in, const int* in_sizes, int n_in,
                              void* d_out, int out_size, void* d_ws, size_t ws_size,
                              hipStream_t stream) {
    const float* x    = (const float*)d_in[0];
    const float* w    = (const float*)d_in[1];
    const float* bias = (const float*)d_in[2];
    float* out = (float*)d_out;
    float* y   = out;
    float* upd = out + Y_SIZE;

    // ws: wH 147456 | winners 492032 | partials 4G*36864 | tmp NS*294912
    const size_t fixed = 147456 + 492032;   // 639488
    short* wHs     = (short*)d_ws;
    int*   winners = (int*)((char*)d_ws + 147456);

    size_t avail = (ws_size > fixed) ? (ws_size - fixed) : 0;
    int G = 256;
    while (G > 1) {
        size_t need = (size_t)4*G*36864 + (size_t)((G + 15)/16)*294912;
        if (need <= avail) break;
        G >>= 1;
    }
    int NS = (G + 15)/16;

    unsigned short* part = (unsigned short*)((char*)d_ws + fixed);
    float* tmp = (float*)((char*)d_ws + fixed + (size_t)4*G*36864);

    wnorm_kernel<<<OC, IC, 0, stream>>>(w, wHs);
    conv_kernel<<<OHW*BATCH, 256, 0, stream>>>(x, wHs, bias, y, winners);
    hebb_kernel<<<4*G, 512, 0, stream>>>(x, winners, part, G);
    final1_kernel<<<288*NS, 256, 0, stream>>>(part, tmp, G, NS);
    final2_kernel<<<288, 256, 0, stream>>>(tmp, upd, NS);
}

// Round 18
// 85.175 us; speedup vs baseline: 1.5776x; 1.0590x over previous
//
#include <hip/hip_runtime.h>
#include <math.h>

typedef __attribute__((ext_vector_type(8))) short bf16x8;
typedef __attribute__((ext_vector_type(4))) float f32x4;

#define IC 64
#define OC 128
#define OHW 62
#define LOCS (OHW*OHW)          /* 3844 */
#define BATCH 32
#define Y_SIZE (BATCH*OC*LOCS)  /* 15740928 */
#define UPD_SIZE (OC*IC*9)      /* 73728 */

#define SWZ(w) (((w) & 7) << 3)

__device__ __forceinline__ unsigned short f2bf(float f) {
    unsigned u = __float_as_uint(f);
    unsigned r = (u + 0x7FFFu + ((u >> 16) & 1u)) >> 16;   // RNE
    return (unsigned short)r;
}
__device__ __forceinline__ float bf2f(unsigned short h) {
    return __uint_as_float(((unsigned)h) << 16);
}
// pack hi16(u1)<<16 | hi16(u0) in ONE v_perm
__device__ __forceinline__ unsigned packhi(unsigned u1, unsigned u0) {
    return __builtin_amdgcn_perm(u1, u0, 0x07060302u);
}

// ---------------- K1: weight norm -> wH burst layout [s=ij*2+ch][lg][k][8c]
__global__ void wnorm_kernel(const float* __restrict__ w, short* __restrict__ wH) {
    int k = blockIdx.x;      // 0..127
    int c = threadIdx.x;     // 0..63
    const float* wp = w + ((size_t)k*IC + c)*9;
    float v[9]; float s = 0.f;
#pragma unroll
    for (int t = 0; t < 9; ++t) { v[t] = wp[t]; s += v[t]*v[t]; }
#pragma unroll
    for (int off = 32; off > 0; off >>= 1) s += __shfl_xor(s, off);
    float nrm = sqrtf(s);
    if (nrm == 0.f) nrm = 1.f;
    float inv = 1.f / nrm;
    const int ch = c >> 5, lg = (c >> 3) & 3, pos = c & 7;
#pragma unroll
    for (int t = 0; t < 9; ++t) {
        size_t off = ((size_t)((t*2 + ch)*4 + lg)*128 + k)*8 + pos;
        wH[off] = (short)f2bf(v[t]*inv);
    }
}

// ---------------- K2: conv via 1-term bf16 MFMA + bias + argmax -----------
// r16 wave mapping (wave = k-band: A read once per block, B-LDS shared);
// A-ring depth 3. 1-D grid 1984 = 8*248, XCD-clustered.
__global__ __launch_bounds__(256, 6) void conv_kernel(
    const float* __restrict__ x, const short* __restrict__ wH,
    const float* __restrict__ bias, float* __restrict__ y,
    int* __restrict__ winners)
{
    __shared__ short xh[3*66*64];    // [i][w(66)][c], bf16 RNE, swizzled; 25344 B
    __shared__ float biasL[OC];

    const int l = blockIdx.x;
    const int v = (l & 7)*248 + (l >> 3);   // bijective: 1984 = 8*248
    const int b = v / OHW;
    const int oh = v - b*OHW;
    const int tid = threadIdx.x;
    if (tid < OC) biasL[tid] = bias[tid];

    // stage x[b,:,oh..oh+2,:] -> bf16 (RNE), transposed [i][w][c]; batched loads
    float4 A0[6], A1[6];
#pragma unroll
    for (int q = 0; q < 6; ++q) {
        int it = tid + q*256;
        int wq = it & 15, c2 = (it >> 4) & 31, i = it >> 9;
        const float* p = x + (((size_t)(b*IC + c2*2))*64 + (oh + i))*64 + wq*4;
        A0[q] = *(const float4*)p;
        A1[q] = *(const float4*)(p + 4096);
    }
#pragma unroll
    for (int q = 0; q < 6; ++q) {
        int it = tid + q*256;
        int wq = it & 15, c2 = (it >> 4) & 31, i = it >> 9;
        int c = c2*2, w0 = wq*4;
        float f0[4] = {A0[q].x, A0[q].y, A0[q].z, A0[q].w};
        float f1[4] = {A1[q].x, A1[q].y, A1[q].z, A1[q].w};
#pragma unroll
        for (int jj = 0; jj < 4; ++jj) {
            int w = w0 + jj;
            unsigned u0 = __float_as_uint(f0[jj]);
            unsigned u1 = __float_as_uint(f1[jj]);
            unsigned r0 = u0 + 0x7FFFu + ((u0 >> 16) & 1u);   // RNE in high 16
            unsigned r1 = u1 + 0x7FFFu + ((u1 >> 16) & 1u);
            unsigned hi = packhi(r1, r0);
            int e = (i*66 + w)*64 + c;
            int widx = (e ^ SWZ(w)) >> 1;      // uint index, swizzled
            ((unsigned*)xh)[widx] = hi;
        }
    }
    __syncthreads();

    const int lane = tid & 63, wv = tid >> 6;
    const int l15 = lane & 15, lg = lane >> 4;
    const int kbase = wv*32;

    f32x4 acc[2][4];
#pragma unroll
    for (int kf = 0; kf < 2; ++kf)
#pragma unroll
        for (int nf = 0; nf < 4; ++nf)
            acc[kf][nf] = (f32x4){0.f,0.f,0.f,0.f};

    // A-frag prefetch ring, depth 3 (slots 4; steps s..s+3 in flight).
    bf16x8 pah[4][2];
#pragma unroll
    for (int ps = 0; ps < 3; ++ps)
#pragma unroll
        for (int kf = 0; kf < 2; ++kf) {
            int k = kbase + kf*16 + l15;
            pah[ps][kf] = *(const bf16x8*)(wH + ((size_t)(ps*4 + lg)*128 + k)*8);
        }

    __builtin_amdgcn_s_setprio(1);
#pragma unroll
    for (int s = 0; s < 18; ++s) {
        const int ij = s >> 1, ch = s & 1;
        const int i = ij / 3, j = ij % 3;
        const int cur = s & 3;
        if (s + 3 < 18) {
            const int nxt = (s + 3) & 3;
#pragma unroll
            for (int kf = 0; kf < 2; ++kf) {
                int k = kbase + kf*16 + l15;
                pah[nxt][kf] = *(const bf16x8*)(wH + ((size_t)((s+3)*4 + lg)*128 + k)*8);
            }
        }
#pragma unroll
        for (int nf = 0; nf < 4; ++nf) {
            int w = nf*16 + l15 + j;
            int e = (i*66 + w)*64 + ch*32 + lg*8;
            int si = e ^ SWZ(w);
            bf16x8 bh = *(const bf16x8*)(xh + si);
#pragma unroll
            for (int kf = 0; kf < 2; ++kf)
                acc[kf][nf] = __builtin_amdgcn_mfma_f32_16x16x32_bf16(pah[cur][kf], bh, acc[kf][nf], 0, 0, 0);
        }
    }
    __builtin_amdgcn_s_setprio(0);

    // all xh reads done -> alias reduction arrays into xh
    __syncthreads();
    float* redv = (float*)xh;           // [4][64]
    int*   redi = ((int*)xh) + 256;     // [4][64]

    // bias + store y + argmax (C/D: row=lg*4+r, col=l15 [m89])
#pragma unroll
    for (int nf = 0; nf < 4; ++nf) {
        int n = nf*16 + l15;
        float vm = -3.4e38f; int im = 0;
#pragma unroll
        for (int kf = 0; kf < 2; ++kf)
#pragma unroll
            for (int r = 0; r < 4; ++r) {
                int k = kbase + kf*16 + lg*4 + r;
                float v2 = acc[kf][nf][r] + biasL[k];
                if (n < OHW) y[(((size_t)b*OC + k)*OHW + oh)*OHW + n] = v2;
                if (v2 > vm) { vm = v2; im = k; }      // ascending k, strict >
            }
        {
            float ov = __shfl_xor(vm, 16); int oi = __shfl_xor(im, 16);
            if (ov > vm || (ov == vm && oi < im)) { vm = ov; im = oi; }
            ov = __shfl_xor(vm, 32); oi = __shfl_xor(im, 32);
            if (ov > vm || (ov == vm && oi < im)) { vm = ov; im = oi; }
        }
        if (lg == 0) { redv[wv*64 + n] = vm; redi[wv*64 + n] = im; }
    }
    __syncthreads();
    if (tid < OHW) {
        float bv = redv[tid]; int bi = redi[tid];
#pragma unroll
        for (int wvv = 1; wvv < 4; ++wvv) {
            float v2 = redv[wvv*64 + tid]; int i2 = redi[wvv*64 + tid];
            if (v2 > bv || (v2 == bv && i2 < bi)) { bv = v2; bi = i2; }
        }
        winners[(size_t)b*LOCS + oh*OHW + tid] = bi;
    }
}

// ---------------- K3: Hebbian via one-hot-mask MFMA, c-quarter partials ---
__global__ __launch_bounds__(512, 4) void hebb_kernel(
    const float* __restrict__ x, const int* __restrict__ winners,
    unsigned short* __restrict__ part, int G)
{
    __shared__ short xR[16*10*72];   // [cLocal][row(10)][72], bf16; 23040 B
    __shared__ int winL[8*64];       // 2048 B

    const int bid = blockIdx.x;
    const int q = bid & 3, g = bid >> 2;
    const int tid = threadIdx.x;
    const int lane = tid & 63, wv = tid >> 6;
    const int l15 = lane & 15, lg = lane >> 4;
    const int myk = wv*16 + l15;

    int off0[3];
#pragma unroll
    for (int nf = 0; nf < 3; ++nf) {
        int npL = nf*16 + l15;           // 0..47 local = cLocal*3+i
        int cL = npL / 3, i = npL % 3;
        off0[nf] = (cL*10 + i)*72;
    }

    f32x4 acc[3][3];
#pragma unroll
    for (int j = 0; j < 3; ++j)
#pragma unroll
        for (int nf = 0; nf < 3; ++nf)
            acc[j][nf] = (f32x4){0.f,0.f,0.f,0.f};

    for (int t = g; t < 256; t += G) {
        const int b = t >> 3, sub = t & 7;
        const int oh0 = sub*8;
        const int NR = (sub == 7) ? 6 : 8;
        const int rows = NR + 2;
        const int cnt = rows >> 1;          // 5 (rows=10) or 4 (rows=8)

        __syncthreads();
        // batched staging: issue all loads first (predicated, static index)
        float4 A[5];
#pragma unroll
        for (int q2 = 0; q2 < 5; ++q2) {
            if (q2 < cnt) {
                int it = tid + q2*512;
                int wq2 = it & 15;
                int t2 = it >> 4;
                int r = t2 % rows, cL = t2 / rows;
                const float* p = x + (((size_t)(b*IC + q*16 + cL))*64 + (oh0 + r))*64 + wq2*4;
                A[q2] = *(const float4*)p;
            }
        }
        int wval = -1;
        const int haveW = tid < NR*64;
        if (haveW) {
            int r = tid >> 6, ow = tid & 63;
            wval = (ow < OHW) ? winners[(size_t)b*LOCS + (oh0 + r)*OHW + ow] : -1;
        }
#pragma unroll
        for (int q2 = 0; q2 < 5; ++q2) {
            if (q2 < cnt) {
                int it = tid + q2*512;
                int wq2 = it & 15;
                int t2 = it >> 4;
                int r = t2 % rows, cL = t2 / rows;
                unsigned u0 = packhi(__float_as_uint(A[q2].y), __float_as_uint(A[q2].x));
                unsigned u1 = packhi(__float_as_uint(A[q2].w), __float_as_uint(A[q2].z));
                int e = (cL*10 + r)*72 + wq2*4;
                ((unsigned*)xR)[e >> 1]       = u0;
                ((unsigned*)xR)[(e >> 1) + 1] = u1;
            }
        }
        if (haveW) winL[tid] = wval;
        __syncthreads();

        for (int r = 0; r < NR; ++r) {
#pragma unroll
            for (int h = 0; h < 2; ++h) {
                const int base = h*32 + lg*8;
                const int* wrow = &winL[r*64];
                int wreg[8];
                *(int4*)&wreg[0] = *(const int4*)&wrow[base];
                *(int4*)&wreg[4] = *(const int4*)&wrow[base + 4];
                const int wm1 = (base >= 1) ? wrow[base-1] : -1;
                const int wm2 = (base >= 2) ? wrow[base-2] : -1;
                union U8 { unsigned u[4]; bf16x8 v; };
                bf16x8 am[3];
#pragma unroll
                for (int j = 0; j < 3; ++j) {
                    U8 tmp;
#pragma unroll
                    for (int p2 = 0; p2 < 4; ++p2) {
                        int t0 = p2*2, t1 = t0 + 1;
                        int s0 = (t0 >= j) ? wreg[t0-j] : ((j - t0 == 1) ? wm1 : wm2);
                        int s1 = (t1 >= j) ? wreg[t1-j] : ((j - t1 == 1) ? wm1 : wm2);
                        tmp.u[p2] = ((s0 == myk) ? 0x3F80u : 0u)
                                  | (((s1 == myk) ? 0x3F80u : 0u) << 16);
                    }
                    am[j] = tmp.v;
                }
#pragma unroll
                for (int nf = 0; nf < 3; ++nf) {
                    const bf16x8 bb = *(const bf16x8*)&xR[off0[nf] + r*72 + base];
#pragma unroll
                    for (int j = 0; j < 3; ++j)
                        acc[j][nf] = __builtin_amdgcn_mfma_f32_16x16x32_bf16(am[j], bb, acc[j][nf], 0, 0, 0);
                }
            }
        }
    }

    // one bf16 partial write per block: part[bid][rowL(144)][k(128)]
    unsigned short* dst = part + (size_t)bid*(144*128);
#pragma unroll
    for (int j = 0; j < 3; ++j)
#pragma unroll
        for (int nf = 0; nf < 3; ++nf) {
            int npL = nf*16 + l15;
            int rowL = npL*3 + j;               // 0..143
            int kc   = wv*16 + lg*4;
            ushort4 o;
            o.x = f2bf(acc[j][nf][0]); o.y = f2bf(acc[j][nf][1]);
            o.z = f2bf(acc[j][nf][2]); o.w = f2bf(acc[j][nf][3]);
            *(ushort4*)(dst + rowL*128 + kc) = o;
        }
}

// ---------------- K4a: stage-A reduction: 16 partials per thread ----------
__global__ __launch_bounds__(256) void final1_kernel(const unsigned short* __restrict__ part,
                                                     float* __restrict__ tmp, int G, int NS) {
    int bid = blockIdx.x;
    int ob = bid % 288, ns = bid / 288;
    int t = ob*256 + threadIdx.x;              // t = row*128 + k
    int k = t & 127, row = t >> 7;
    int q = row / 144;
    int rowL = row - q*144;
    int g0 = ns*16, g1 = g0 + 16; if (g1 > G) g1 = G;
    float s = 0.f;
#pragma unroll 4
    for (int g = g0; g < g1; ++g)
        s += bf2f(part[((size_t)(g*4 + q))*(144*128) + rowL*128 + k]);
    tmp[(size_t)ns*UPD_SIZE + t] = s;
}

// ---------------- K4b: stage-B: sum NS floats + scale + transpose ---------
__global__ __launch_bounds__(256) void final2_kernel(const float* __restrict__ tmp,
                                                     float* __restrict__ upd, int NS) {
    int t = blockIdx.x*256 + threadIdx.x;      // t = row*128 + k
    int k = t & 127, row = t >> 7;
    float s = 0.f;
    for (int ns = 0; ns < NS; ++ns)
        s += tmp[(size_t)ns*UPD_SIZE + t];
    upd[(size_t)k*576 + row] = s * (1.0f/123008.0f);
}

extern "C" void kernel_launch(void* const* d_in, const int* in_sizes, int n_in,
                              void* d_out, int out_size, void* d_ws, size_t ws_size,
                              hipStream_t stream) {
    const float* x    = (const float*)d_in[0];
    const float* w    = (const float*)d_in[1];
    const float* bias = (const float*)d_in[2];
    float* out = (float*)d_out;
    float* y   = out;
    float* upd = out + Y_SIZE;

    // ws: wH 147456 | winners 492032 | partials 4G*36864 | tmp NS*294912
    const size_t fixed = 147456 + 492032;   // 639488
    short* wHs     = (short*)d_ws;
    int*   winners = (int*)((char*)d_ws + 147456);

    size_t avail = (ws_size > fixed) ? (ws_size - fixed) : 0;
    int G = 256;
    while (G > 1) {
        size_t need = (size_t)4*G*36864 + (size_t)((G + 15)/16)*294912;
        if (need <= avail) break;
        G >>= 1;
    }
    int NS = (G + 15)/16;

    unsigned short* part = (unsigned short*)((char*)d_ws + fixed);
    float* tmp = (float*)((char*)d_ws + fixed + (size_t)4*G*36864);

    wnorm_kernel<<<OC, IC, 0, stream>>>(w, wHs);
    conv_kernel<<<OHW*BATCH, 256, 0, stream>>>(x, wHs, bias, y, winners);
    hebb_kernel<<<4*G, 512, 0, stream>>>(x, winners, part, G);
    final1_kernel<<<288*NS, 256, 0, stream>>>(part, tmp, G, NS);
    final2_kernel<<<288, 256, 0, stream>>>(tmp, upd, NS);
}

// Round 19
// 84.725 us; speedup vs baseline: 1.5860x; 1.0053x over previous
//
#include <hip/hip_runtime.h>
#include <math.h>

typedef __attribute__((ext_vector_type(8))) short bf16x8;
typedef __attribute__((ext_vector_type(4))) float f32x4;

#define IC 64
#define OC 128
#define OHW 62
#define LOCS (OHW*OHW)          /* 3844 */
#define BATCH 32
#define Y_SIZE (BATCH*OC*LOCS)  /* 15740928 */
#define UPD_SIZE (OC*IC*9)      /* 73728 */

#define SWZ(w) (((w) & 7) << 3)

__device__ __forceinline__ unsigned short f2bf(float f) {
    unsigned u = __float_as_uint(f);
    unsigned r = (u + 0x7FFFu + ((u >> 16) & 1u)) >> 16;   // RNE
    return (unsigned short)r;
}
__device__ __forceinline__ float bf2f(unsigned short h) {
    return __uint_as_float(((unsigned)h) << 16);
}
// pack hi16(u1)<<16 | hi16(u0) in ONE v_perm
__device__ __forceinline__ unsigned packhi(unsigned u1, unsigned u0) {
    return __builtin_amdgcn_perm(u1, u0, 0x07060302u);
}

// ---------------- K1: weight norm -> wH burst layout [s=ij*2+ch][lg][k][8c]
__global__ void wnorm_kernel(const float* __restrict__ w, short* __restrict__ wH) {
    int k = blockIdx.x;      // 0..127
    int c = threadIdx.x;     // 0..63
    const float* wp = w + ((size_t)k*IC + c)*9;
    float v[9]; float s = 0.f;
#pragma unroll
    for (int t = 0; t < 9; ++t) { v[t] = wp[t]; s += v[t]*v[t]; }
#pragma unroll
    for (int off = 32; off > 0; off >>= 1) s += __shfl_xor(s, off);
    float nrm = sqrtf(s);
    if (nrm == 0.f) nrm = 1.f;
    float inv = 1.f / nrm;
    const int ch = c >> 5, lg = (c >> 3) & 3, pos = c & 7;
#pragma unroll
    for (int t = 0; t < 9; ++t) {
        size_t off = ((size_t)((t*2 + ch)*4 + lg)*128 + k)*8 + pos;
        wH[off] = (short)f2bf(v[t]*inv);
    }
}

// ---------------- K2: conv via 1-term bf16 MFMA + bias + argmax -----------
// r16 wave mapping (wave = k-band); A-ring depth 3; XCD-clustered grid.
__global__ __launch_bounds__(256, 6) void conv_kernel(
    const float* __restrict__ x, const short* __restrict__ wH,
    const float* __restrict__ bias, float* __restrict__ y,
    int* __restrict__ winners)
{
    __shared__ short xh[3*66*64];    // [i][w(66)][c], bf16 RNE, swizzled; 25344 B
    __shared__ float biasL[OC];

    const int l = blockIdx.x;
    const int v = (l & 7)*248 + (l >> 3);   // bijective: 1984 = 8*248
    const int b = v / OHW;
    const int oh = v - b*OHW;
    const int tid = threadIdx.x;
    if (tid < OC) biasL[tid] = bias[tid];

    // stage x[b,:,oh..oh+2,:] -> bf16 (RNE), transposed [i][w][c]; batched loads
    float4 A0[6], A1[6];
#pragma unroll
    for (int q = 0; q < 6; ++q) {
        int it = tid + q*256;
        int wq = it & 15, c2 = (it >> 4) & 31, i = it >> 9;
        const float* p = x + (((size_t)(b*IC + c2*2))*64 + (oh + i))*64 + wq*4;
        A0[q] = *(const float4*)p;
        A1[q] = *(const float4*)(p + 4096);
    }
#pragma unroll
    for (int q = 0; q < 6; ++q) {
        int it = tid + q*256;
        int wq = it & 15, c2 = (it >> 4) & 31, i = it >> 9;
        int c = c2*2, w0 = wq*4;
        float f0[4] = {A0[q].x, A0[q].y, A0[q].z, A0[q].w};
        float f1[4] = {A1[q].x, A1[q].y, A1[q].z, A1[q].w};
#pragma unroll
        for (int jj = 0; jj < 4; ++jj) {
            int w = w0 + jj;
            unsigned u0 = __float_as_uint(f0[jj]);
            unsigned u1 = __float_as_uint(f1[jj]);
            unsigned r0 = u0 + 0x7FFFu + ((u0 >> 16) & 1u);   // RNE in high 16
            unsigned r1 = u1 + 0x7FFFu + ((u1 >> 16) & 1u);
            unsigned hi = packhi(r1, r0);
            int e = (i*66 + w)*64 + c;
            int widx = (e ^ SWZ(w)) >> 1;      // uint index, swizzled
            ((unsigned*)xh)[widx] = hi;
        }
    }
    __syncthreads();

    const int lane = tid & 63, wv = tid >> 6;
    const int l15 = lane & 15, lg = lane >> 4;
    const int kbase = wv*32;

    f32x4 acc[2][4];
#pragma unroll
    for (int kf = 0; kf < 2; ++kf)
#pragma unroll
        for (int nf = 0; nf < 4; ++nf)
            acc[kf][nf] = (f32x4){0.f,0.f,0.f,0.f};

    // A-frag prefetch ring, depth 3 (slots 4; steps s..s+3 in flight).
    bf16x8 pah[4][2];
#pragma unroll
    for (int ps = 0; ps < 3; ++ps)
#pragma unroll
        for (int kf = 0; kf < 2; ++kf) {
            int k = kbase + kf*16 + l15;
            pah[ps][kf] = *(const bf16x8*)(wH + ((size_t)(ps*4 + lg)*128 + k)*8);
        }

    __builtin_amdgcn_s_setprio(1);
#pragma unroll
    for (int s = 0; s < 18; ++s) {
        const int ij = s >> 1, ch = s & 1;
        const int i = ij / 3, j = ij % 3;
        const int cur = s & 3;
        if (s + 3 < 18) {
            const int nxt = (s + 3) & 3;
#pragma unroll
            for (int kf = 0; kf < 2; ++kf) {
                int k = kbase + kf*16 + l15;
                pah[nxt][kf] = *(const bf16x8*)(wH + ((size_t)((s+3)*4 + lg)*128 + k)*8);
            }
        }
#pragma unroll
        for (int nf = 0; nf < 4; ++nf) {
            int w = nf*16 + l15 + j;
            int e = (i*66 + w)*64 + ch*32 + lg*8;
            int si = e ^ SWZ(w);
            bf16x8 bh = *(const bf16x8*)(xh + si);
#pragma unroll
            for (int kf = 0; kf < 2; ++kf)
                acc[kf][nf] = __builtin_amdgcn_mfma_f32_16x16x32_bf16(pah[cur][kf], bh, acc[kf][nf], 0, 0, 0);
        }
    }
    __builtin_amdgcn_s_setprio(0);

    // all xh reads done -> alias reduction arrays into xh
    __syncthreads();
    float* redv = (float*)xh;           // [4][64]
    int*   redi = ((int*)xh) + 256;     // [4][64]

    // bias + store y + argmax (C/D: row=lg*4+r, col=l15 [m89])
#pragma unroll
    for (int nf = 0; nf < 4; ++nf) {
        int n = nf*16 + l15;
        float vm = -3.4e38f; int im = 0;
#pragma unroll
        for (int kf = 0; kf < 2; ++kf)
#pragma unroll
            for (int r = 0; r < 4; ++r) {
                int k = kbase + kf*16 + lg*4 + r;
                float v2 = acc[kf][nf][r] + biasL[k];
                if (n < OHW) y[(((size_t)b*OC + k)*OHW + oh)*OHW + n] = v2;
                if (v2 > vm) { vm = v2; im = k; }      // ascending k, strict >
            }
        {
            float ov = __shfl_xor(vm, 16); int oi = __shfl_xor(im, 16);
            if (ov > vm || (ov == vm && oi < im)) { vm = ov; im = oi; }
            ov = __shfl_xor(vm, 32); oi = __shfl_xor(im, 32);
            if (ov > vm || (ov == vm && oi < im)) { vm = ov; im = oi; }
        }
        if (lg == 0) { redv[wv*64 + n] = vm; redi[wv*64 + n] = im; }
    }
    __syncthreads();
    if (tid < OHW) {
        float bv = redv[tid]; int bi = redi[tid];
#pragma unroll
        for (int wvv = 1; wvv < 4; ++wvv) {
            float v2 = redv[wvv*64 + tid]; int i2 = redi[wvv*64 + tid];
            if (v2 > bv || (v2 == bv && i2 < bi)) { bv = v2; bi = i2; }
        }
        winners[(size_t)b*LOCS + oh*OHW + tid] = bi;
    }
}

// ---------------- K3: Hebbian via one-hot-mask MFMA, c-quarter partials ---
// mask-build hoisted: eq[10] computed once per (r,h), am[j] = static packs.
__global__ __launch_bounds__(512, 4) void hebb_kernel(
    const float* __restrict__ x, const int* __restrict__ winners,
    unsigned short* __restrict__ part, int G)
{
    __shared__ short xR[16*10*72];   // [cLocal][row(10)][72], bf16; 23040 B
    __shared__ int winL[8*64];       // 2048 B

    const int bid = blockIdx.x;
    const int q = bid & 3, g = bid >> 2;
    const int tid = threadIdx.x;
    const int lane = tid & 63, wv = tid >> 6;
    const int l15 = lane & 15, lg = lane >> 4;
    const int myk = wv*16 + l15;

    int off0[3];
#pragma unroll
    for (int nf = 0; nf < 3; ++nf) {
        int npL = nf*16 + l15;           // 0..47 local = cLocal*3+i
        int cL = npL / 3, i = npL % 3;
        off0[nf] = (cL*10 + i)*72;
    }

    f32x4 acc[3][3];
#pragma unroll
    for (int j = 0; j < 3; ++j)
#pragma unroll
        for (int nf = 0; nf < 3; ++nf)
            acc[j][nf] = (f32x4){0.f,0.f,0.f,0.f};

    for (int t = g; t < 256; t += G) {
        const int b = t >> 3, sub = t & 7;
        const int oh0 = sub*8;
        const int NR = (sub == 7) ? 6 : 8;
        const int rows = NR + 2;
        const int cnt = rows >> 1;          // 5 (rows=10) or 4 (rows=8)

        __syncthreads();
        // batched staging: issue all loads first (predicated, static index)
        float4 A[5];
#pragma unroll
        for (int q2 = 0; q2 < 5; ++q2) {
            if (q2 < cnt) {
                int it = tid + q2*512;
                int wq2 = it & 15;
                int t2 = it >> 4;
                int r = t2 % rows, cL = t2 / rows;
                const float* p = x + (((size_t)(b*IC + q*16 + cL))*64 + (oh0 + r))*64 + wq2*4;
                A[q2] = *(const float4*)p;
            }
        }
        int wval = -1;
        const int haveW = tid < NR*64;
        if (haveW) {
            int r = tid >> 6, ow = tid & 63;
            wval = (ow < OHW) ? winners[(size_t)b*LOCS + (oh0 + r)*OHW + ow] : -1;
        }
#pragma unroll
        for (int q2 = 0; q2 < 5; ++q2) {
            if (q2 < cnt) {
                int it = tid + q2*512;
                int wq2 = it & 15;
                int t2 = it >> 4;
                int r = t2 % rows, cL = t2 / rows;
                unsigned u0 = packhi(__float_as_uint(A[q2].y), __float_as_uint(A[q2].x));
                unsigned u1 = packhi(__float_as_uint(A[q2].w), __float_as_uint(A[q2].z));
                int e = (cL*10 + r)*72 + wq2*4;
                ((unsigned*)xR)[e >> 1]       = u0;
                ((unsigned*)xR)[(e >> 1) + 1] = u1;
            }
        }
        if (haveW) winL[tid] = wval;
        __syncthreads();

        for (int r = 0; r < NR; ++r) {
#pragma unroll
            for (int h = 0; h < 2; ++h) {
                const int base = h*32 + lg*8;
                const int* wrow = &winL[r*64];
                int wreg[8];
                *(int4*)&wreg[0] = *(const int4*)&wrow[base];
                *(int4*)&wreg[4] = *(const int4*)&wrow[base + 4];
                const int wm1 = (base >= 1) ? wrow[base-1] : -1;
                const int wm2 = (base >= 2) ? wrow[base-2] : -1;
                // hoisted one-hot: eq[2+t] for wreg[t], eq[1]=wm1, eq[0]=wm2
                unsigned eq[10];
                eq[0] = (wm2 == myk) ? 0x3F80u : 0u;
                eq[1] = (wm1 == myk) ? 0x3F80u : 0u;
#pragma unroll
                for (int t2 = 0; t2 < 8; ++t2)
                    eq[2 + t2] = (wreg[t2] == myk) ? 0x3F80u : 0u;
                union U8 { unsigned u[4]; bf16x8 v; };
                bf16x8 am[3];
#pragma unroll
                for (int j = 0; j < 3; ++j) {
                    U8 tmp;
#pragma unroll
                    for (int p2 = 0; p2 < 4; ++p2)
                        tmp.u[p2] = eq[2 + p2*2 - j] | (eq[3 + p2*2 - j] << 16);
                    am[j] = tmp.v;
                }
#pragma unroll
                for (int nf = 0; nf < 3; ++nf) {
                    const bf16x8 bb = *(const bf16x8*)&xR[off0[nf] + r*72 + base];
#pragma unroll
                    for (int j = 0; j < 3; ++j)
                        acc[j][nf] = __builtin_amdgcn_mfma_f32_16x16x32_bf16(am[j], bb, acc[j][nf], 0, 0, 0);
                }
            }
        }
    }

    // one bf16 partial write per block: part[bid][rowL(144)][k(128)]
    unsigned short* dst = part + (size_t)bid*(144*128);
#pragma unroll
    for (int j = 0; j < 3; ++j)
#pragma unroll
        for (int nf = 0; nf < 3; ++nf) {
            int npL = nf*16 + l15;
            int rowL = npL*3 + j;               // 0..143
            int kc   = wv*16 + lg*4;
            ushort4 o;
            o.x = f2bf(acc[j][nf][0]); o.y = f2bf(acc[j][nf][1]);
            o.z = f2bf(acc[j][nf][2]); o.w = f2bf(acc[j][nf][3]);
            *(ushort4*)(dst + rowL*128 + kc) = o;
        }
}

// ---------------- K4a: stage-A reduction: 16 partials per thread ----------
__global__ __launch_bounds__(256) void final1_kernel(const unsigned short* __restrict__ part,
                                                     float* __restrict__ tmp, int G, int NS) {
    int bid = blockIdx.x;
    int ob = bid % 288, ns = bid / 288;
    int t = ob*256 + threadIdx.x;              // t = row*128 + k
    int k = t & 127, row = t >> 7;
    int q = row / 144;
    int rowL = row - q*144;
    int g0 = ns*16, g1 = g0 + 16; if (g1 > G) g1 = G;
    float s = 0.f;
#pragma unroll 4
    for (int g = g0; g < g1; ++g)
        s += bf2f(part[((size_t)(g*4 + q))*(144*128) + rowL*128 + k]);
    tmp[(size_t)ns*UPD_SIZE + t] = s;
}

// ---------------- K4b: stage-B: sum NS floats + scale + transpose ---------
__global__ __launch_bounds__(256) void final2_kernel(const float* __restrict__ tmp,
                                                     float* __restrict__ upd, int NS) {
    int t = blockIdx.x*256 + threadIdx.x;      // t = row*128 + k
    int k = t & 127, row = t >> 7;
    float s = 0.f;
    for (int ns = 0; ns < NS; ++ns)
        s += tmp[(size_t)ns*UPD_SIZE + t];
    upd[(size_t)k*576 + row] = s * (1.0f/123008.0f);
}

extern "C" void kernel_launch(void* const* d_in, const int* in_sizes, int n_in,
                              void* d_out, int out_size, void* d_ws, size_t ws_size,
                              hipStream_t stream) {
    const float* x    = (const float*)d_in[0];
    const float* w    = (const float*)d_in[1];
    const float* bias = (const float*)d_in[2];
    float* out = (float*)d_out;
    float* y   = out;
    float* upd = out + Y_SIZE;

    // ws: wH 147456 | winners 492032 | partials 4G*36864 | tmp NS*294912
    const size_t fixed = 147456 + 492032;   // 639488
    short* wHs     = (short*)d_ws;
    int*   winners = (int*)((char*)d_ws + 147456);

    size_t avail = (ws_size > fixed) ? (ws_size - fixed) : 0;
    int G = 256;
    while (G > 1) {
        size_t need = (size_t)4*G*36864 + (size_t)((G + 15)/16)*294912;
        if (need <= avail) break;
        G >>= 1;
    }
    int NS = (G + 15)/16;

    unsigned short* part = (unsigned short*)((char*)d_ws + fixed);
    float* tmp = (float*)((char*)d_ws + fixed + (size_t)4*G*36864);

    wnorm_kernel<<<OC, IC, 0, stream>>>(w, wHs);
    conv_kernel<<<OHW*BATCH, 256, 0, stream>>>(x, wHs, bias, y, winners);
    hebb_kernel<<<4*G, 512, 0, stream>>>(x, winners, part, G);
    final1_kernel<<<288*NS, 256, 0, stream>>>(part, tmp, G, NS);
    final2_kernel<<<288, 256, 0, stream>>>(tmp, upd, NS);
}